// Round 3
// baseline (301.157 us; speedup 1.0000x reference)
//
#include <hip/hip_runtime.h>

namespace {
constexpr int NB = 256, NN = 1024, DIN = 64, HID = 256, DOUT = 128;
constexpr int SPLIT = 2;
constexpr int CHUNK = NN / SPLIT;     // 512 elements per block
constexpr int MT = 128;               // rows per phi tile
constexpr int XPAD = 72;              // xs row stride (bf16), 144B = 16B-aligned
constexpr int HPAD = 264;             // h1s row stride (bf16), 528B = 16B-aligned

typedef __attribute__((ext_vector_type(8))) short bf16x8;
typedef __attribute__((ext_vector_type(4))) float f32x4;

// ws layout: pooled[NB*HID] f32, cnts[NB] i32, w1p bf16, w2p bf16
constexpr size_t POOLED_OFF = 0;
constexpr size_t CNTS_OFF   = (size_t)NB * HID * 4;                 // 256 KB
constexpr size_t PW1_OFF    = CNTS_OFF + (size_t)NB * 4;            // +1 KB
constexpr size_t PW2_OFF    = PW1_OFF + (size_t)DIN * HID * 2;      // +32 KB
constexpr int ZERO_N = NB * HID + NB;                               // 65792 floats/ints

__device__ inline unsigned short f2bf(float f) {   // RNE float->bf16
    union { float f; unsigned u; } v; v.f = f;
    unsigned r = v.u + 0x7FFF + ((v.u >> 16) & 1);
    return (unsigned short)(r >> 16);
}

// ---- kernel 0: zero pooled+cnts, pack W1/W2 into MFMA B-frag order ----
// B-frag (16x16x32): lane holds W[k0+(lane>>4)*8+j][n0+(lane&15)], j=0..7.
// packed linear: w1p: strip*1024 + kk*512 + lane*8 + j   (strip=n>>4, kk=k>>5)
//                w2p: strip*4096 + kk*512 + lane*8 + j
__global__ void prep(const float* __restrict__ pw1, const float* __restrict__ pw2,
                     float* __restrict__ zero_base,
                     unsigned short* __restrict__ w1p, unsigned short* __restrict__ w2p) {
    int i = blockIdx.x * 256 + threadIdx.x;
    if (i < ZERO_N) zero_base[i] = 0.f;
    if (i < DIN * HID / 8) {            // 2048 threads, 8 consecutive src elems each
        int s0 = i * 8;
        int k = s0 >> 8, n0 = s0 & 255;
        float4 v0 = *(const float4*)(pw1 + s0);
        float4 v1 = *(const float4*)(pw1 + s0 + 4);
        float vv[8] = {v0.x, v0.y, v0.z, v0.w, v1.x, v1.y, v1.z, v1.w};
        int j = k & 7, quad = (k >> 3) & 3, kk = k >> 5;
#pragma unroll
        for (int e = 0; e < 8; ++e) {
            int n = n0 + e, strip = n >> 4, l15 = n & 15;
            w1p[strip * 1024 + kk * 512 + (quad * 16 + l15) * 8 + j] = f2bf(vv[e]);
        }
    }
    if (i < HID * HID / 8) {            // 8192 threads
        int s0 = i * 8;
        int k = s0 >> 8, n0 = s0 & 255;
        float4 v0 = *(const float4*)(pw2 + s0);
        float4 v1 = *(const float4*)(pw2 + s0 + 4);
        float vv[8] = {v0.x, v0.y, v0.z, v0.w, v1.x, v1.y, v1.z, v1.w};
        int j = k & 7, quad = (k >> 3) & 3, kk = k >> 5;
#pragma unroll
        for (int e = 0; e < 8; ++e) {
            int n = n0 + e, strip = n >> 4, l15 = n & 15;
            w2p[strip * 4096 + kk * 512 + (quad * 16 + l15) * 8 + j] = f2bf(vv[e]);
        }
    }
}

// ---- kernel 1: phi (2 bf16 MFMA layers) + masked pool ----
__launch_bounds__(512, 2)
__global__ void phi_pool(const float* __restrict__ x, const int* __restrict__ mask,
                         const float* __restrict__ pb1, const float* __restrict__ pb2,
                         const unsigned short* __restrict__ w1p,
                         const unsigned short* __restrict__ w2p,
                         float* __restrict__ pooled, int* __restrict__ cnts) {
    __shared__ unsigned short xs[MT * XPAD];    // 18.4 KB
    __shared__ unsigned short h1s[MT * HPAD];   // 67.6 KB
    __shared__ short vlist[CHUNK];              // 1 KB
    __shared__ int cnt_s;

    const int b = blockIdx.x, sp = blockIdx.y;
    const int t = threadIdx.x;
    const int lane = t & 63, wid = t >> 6;      // 8 waves
    const int quad = lane >> 4, l15 = lane & 15;
    const int half = wid & 1;                   // col half: cols half*128
    const int rg   = wid >> 1;                  // row group: rows rg*32..+31

    if (t == 0) cnt_s = 0;
    __syncthreads();
    {
        int n = sp * CHUNK + t;                 // 512 threads cover the chunk
        if (mask[b * NN + n] != 0) { int idx = atomicAdd(&cnt_s, 1); vlist[idx] = (short)n; }
    }
    __syncthreads();
    const int cnt = cnt_s;
    if (t == 0) atomicAdd(&cnts[b], cnt);

    float bias1[8], bias2[8];
#pragma unroll
    for (int j = 0; j < 8; ++j) {
        int c = half * 128 + j * 16 + l15;
        bias1[j] = pb1[c]; bias2[j] = pb2[c];
    }

    float pool[8];
#pragma unroll
    for (int j = 0; j < 8; ++j) pool[j] = 0.f;

    const float* xb = x + (size_t)b * NN * DIN;
    const uint4* w1q = (const uint4*)w1p;
    const uint4* w2q = (const uint4*)w2p;

    for (int base = 0; base < cnt; base += MT) {
        const int rows = min(MT, cnt - base);
        __syncthreads();                        // prior tile's readers done

        // ---- gather x rows -> bf16 LDS tile (zeros for invalid rows) ----
        {
            int r = t >> 2, c0 = (t & 3) * 16;
            float fv[16];
#pragma unroll
            for (int i = 0; i < 16; ++i) fv[i] = 0.f;
            if (r < rows) {
                const float4* s4 = (const float4*)(xb + (size_t)vlist[base + r] * DIN + c0);
                float4 a = s4[0], bq = s4[1], cq = s4[2], dq = s4[3];
                fv[0]=a.x; fv[1]=a.y; fv[2]=a.z; fv[3]=a.w;
                fv[4]=bq.x; fv[5]=bq.y; fv[6]=bq.z; fv[7]=bq.w;
                fv[8]=cq.x; fv[9]=cq.y; fv[10]=cq.z; fv[11]=cq.w;
                fv[12]=dq.x; fv[13]=dq.y; fv[14]=dq.z; fv[15]=dq.w;
            }
            unsigned short tmp[16];
#pragma unroll
            for (int i = 0; i < 16; ++i) tmp[i] = f2bf(fv[i]);
            uint4* dst = (uint4*)&xs[r * XPAD + c0];
            dst[0] = ((const uint4*)tmp)[0];
            dst[1] = ((const uint4*)tmp)[1];
        }
        __syncthreads();

        // ---- layer 1: wave tile 32 rows x 128 cols, K=64 ----
        f32x4 acc1[2][8];
#pragma unroll
        for (int f = 0; f < 2; ++f)
#pragma unroll
            for (int j = 0; j < 8; ++j) acc1[f][j] = (f32x4){0.f, 0.f, 0.f, 0.f};
#pragma unroll
        for (int kk = 0; kk < 2; ++kk) {
            bf16x8 a0 = *(const bf16x8*)&xs[(rg * 32 + l15) * XPAD + kk * 32 + quad * 8];
            bf16x8 a1 = *(const bf16x8*)&xs[(rg * 32 + 16 + l15) * XPAD + kk * 32 + quad * 8];
#pragma unroll
            for (int j = 0; j < 8; ++j) {
                bf16x8 bf = __builtin_bit_cast(bf16x8, w1q[((half * 8 + j) * 2 + kk) * 64 + lane]);
                acc1[0][j] = __builtin_amdgcn_mfma_f32_16x16x32_bf16(a0, bf, acc1[0][j], 0, 0, 0);
                acc1[1][j] = __builtin_amdgcn_mfma_f32_16x16x32_bf16(a1, bf, acc1[1][j], 0, 0, 0);
            }
        }
#pragma unroll
        for (int f = 0; f < 2; ++f)
#pragma unroll
            for (int j = 0; j < 8; ++j)
#pragma unroll
                for (int r = 0; r < 4; ++r) {
                    float h = fmaxf(acc1[f][j][r] + bias1[j], 0.f);
                    int row = rg * 32 + f * 16 + quad * 4 + r;
                    int col = half * 128 + j * 16 + l15;
                    h1s[row * HPAD + col] = f2bf(h);
                }
        __syncthreads();

        // ---- layer 2: K=256, B-frags double-buffered from L2 ----
        f32x4 acc2[2][8];
#pragma unroll
        for (int f = 0; f < 2; ++f)
#pragma unroll
            for (int j = 0; j < 8; ++j) acc2[f][j] = (f32x4){0.f, 0.f, 0.f, 0.f};

        uint4 bcur[8], bnxt[8];
#pragma unroll
        for (int j = 0; j < 8; ++j)
            bcur[j] = w2q[((half * 8 + j) * 8 + 0) * 64 + lane];

#pragma unroll
        for (int kk = 0; kk < 8; ++kk) {
            if (kk < 7) {
#pragma unroll
                for (int j = 0; j < 8; ++j)
                    bnxt[j] = w2q[((half * 8 + j) * 8 + kk + 1) * 64 + lane];
            }
            bf16x8 a0 = *(const bf16x8*)&h1s[(rg * 32 + l15) * HPAD + kk * 32 + quad * 8];
            bf16x8 a1 = *(const bf16x8*)&h1s[(rg * 32 + 16 + l15) * HPAD + kk * 32 + quad * 8];
#pragma unroll
            for (int j = 0; j < 8; ++j) {
                bf16x8 bf = __builtin_bit_cast(bf16x8, bcur[j]);
                acc2[0][j] = __builtin_amdgcn_mfma_f32_16x16x32_bf16(a0, bf, acc2[0][j], 0, 0, 0);
                acc2[1][j] = __builtin_amdgcn_mfma_f32_16x16x32_bf16(a1, bf, acc2[1][j], 0, 0, 0);
            }
#pragma unroll
            for (int j = 0; j < 8; ++j) bcur[j] = bnxt[j];
        }

        // predicated relu+pool
#pragma unroll
        for (int f = 0; f < 2; ++f)
#pragma unroll
            for (int r = 0; r < 4; ++r) {
                bool v = (base + rg * 32 + f * 16 + quad * 4 + r) < cnt;
#pragma unroll
                for (int j = 0; j < 8; ++j) {
                    float h = fmaxf(acc2[f][j][r] + bias2[j], 0.f);
                    pool[j] += v ? h : 0.f;
                }
            }
    }

    // reduce over quad (rows within wave), one atomic per col per wave
#pragma unroll
    for (int j = 0; j < 8; ++j) {
        float v = pool[j];
        v += __shfl_xor(v, 16, 64);
        v += __shfl_xor(v, 32, 64);
        if (quad == 0) atomicAdd(&pooled[b * HID + half * 128 + j * 16 + l15], v);
    }
}

// ---- kernel 2: folded pw3 + rho chain, fp32, ILP-4 ----
__device__ inline float dot256_ilp4(const float* __restrict__ buf,
                                    const float* __restrict__ W, int t, int N) {
    float a0 = 0.f, a1 = 0.f, a2 = 0.f, a3 = 0.f;
#pragma unroll 4
    for (int g = 0; g < HID / 4; ++g) {
        float4 v = *(const float4*)&buf[g * 4];
        const float* wp = W + (size_t)(g * 4) * N + t;
        a0 = fmaf(v.x, wp[0],     a0);
        a1 = fmaf(v.y, wp[N],     a1);
        a2 = fmaf(v.z, wp[2 * N], a2);
        a3 = fmaf(v.w, wp[3 * N], a3);
    }
    return (a0 + a1) + (a2 + a3);
}

__launch_bounds__(256, 4)
__global__ void rho(const float* __restrict__ pooled, const int* __restrict__ cnts,
                    const float* __restrict__ pw3, const float* __restrict__ pb3,
                    const float* __restrict__ rw1, const float* __restrict__ rb1,
                    const float* __restrict__ rw2, const float* __restrict__ rb2,
                    const float* __restrict__ rw3, const float* __restrict__ rb3,
                    float* __restrict__ out) {
    __shared__ float bufA[HID], bufB[HID];
    const int b = blockIdx.x, t = threadIdx.x;
    const int cnt = cnts[b];
    bufA[t] = pooled[b * HID + t];
    __syncthreads();

    bufB[t] = dot256_ilp4(bufA, pw3, t, HID) + (float)cnt * pb3[t];
    __syncthreads();
    bufA[t] = fmaxf(dot256_ilp4(bufB, rw1, t, HID) + rb1[t], 0.f);
    __syncthreads();
    bufB[t] = fmaxf(dot256_ilp4(bufA, rw2, t, HID) + rb2[t], 0.f);
    __syncthreads();
    if (t < DOUT) {
        float o3 = dot256_ilp4(bufB, rw3, t, DOUT) + rb3[t];
        out[b * DOUT + t] = (cnt > 0) ? o3 : 0.f;
    }
}
} // namespace

extern "C" void kernel_launch(void* const* d_in, const int* in_sizes, int n_in,
                              void* d_out, int out_size, void* d_ws, size_t ws_size,
                              hipStream_t stream) {
    const float* x    = (const float*)d_in[0];
    const int*   mask = (const int*)  d_in[1];
    const float* pw1  = (const float*)d_in[2];
    const float* pb1  = (const float*)d_in[3];
    const float* pw2  = (const float*)d_in[4];
    const float* pb2  = (const float*)d_in[5];
    const float* pw3  = (const float*)d_in[6];
    const float* pb3  = (const float*)d_in[7];
    const float* rw1  = (const float*)d_in[8];
    const float* rb1  = (const float*)d_in[9];
    const float* rw2  = (const float*)d_in[10];
    const float* rb2  = (const float*)d_in[11];
    const float* rw3  = (const float*)d_in[12];
    const float* rb3  = (const float*)d_in[13];
    float* out = (float*)d_out;

    float* pooled       = (float*)((char*)d_ws + POOLED_OFF);
    int*   cnts         = (int*)  ((char*)d_ws + CNTS_OFF);
    unsigned short* w1p = (unsigned short*)((char*)d_ws + PW1_OFF);
    unsigned short* w2p = (unsigned short*)((char*)d_ws + PW2_OFF);

    prep<<<dim3((ZERO_N + 255) / 256), dim3(256), 0, stream>>>(pw1, pw2, (float*)d_ws, w1p, w2p);
    phi_pool<<<dim3(NB, SPLIT), dim3(512), 0, stream>>>(x, mask, pb1, pb2, w1p, w2p, pooled, cnts);
    rho<<<dim3(NB), dim3(256), 0, stream>>>(pooled, cnts, pw3, pb3,
                                            rw1, rb1, rw2, rb2, rw3, rb3, out);
}

// Round 4
// 203.035 us; speedup vs baseline: 1.4833x; 1.4833x over previous
//
#include <hip/hip_runtime.h>

namespace {
constexpr int NB = 256, NN = 1024, DIN = 64, HID = 256, DOUT = 128;
constexpr int SPLIT = 3;              // 768 blocks = 3 per CU exactly, one round
constexpr int MT = 64;                // rows per phi tile
constexpr int XPAD = 72;              // xs row stride (bf16), 144B
constexpr int HPAD = 264;             // h1s row stride (bf16), 528B
constexpr int VMAX = 344;

typedef __attribute__((ext_vector_type(8))) short bf16x8;
typedef __attribute__((ext_vector_type(4))) float f32x4;

// ws layout: pooled[NB*HID] f32, cnts[NB] i32, w1p bf16, w2p bf16
constexpr size_t POOLED_OFF = 0;
constexpr size_t CNTS_OFF   = (size_t)NB * HID * 4;
constexpr size_t PW1_OFF    = CNTS_OFF + (size_t)NB * 4;
constexpr size_t PW2_OFF    = PW1_OFF + (size_t)DIN * HID * 2;
constexpr int ZERO_N = NB * HID + NB;

__device__ inline unsigned short f2bf(float f) {   // RNE float->bf16
    union { float f; unsigned u; } v; v.f = f;
    unsigned r = v.u + 0x7FFF + ((v.u >> 16) & 1);
    return (unsigned short)(r >> 16);
}

// ---- kernel 0: zero pooled+cnts, pack W1/W2 into MFMA B-frag order ----
// B-frag (16x16x32): lane holds W[k0+(lane>>4)*8+j][n0+(lane&15)], j=0..7.
__global__ void prep(const float* __restrict__ pw1, const float* __restrict__ pw2,
                     float* __restrict__ zero_base,
                     unsigned short* __restrict__ w1p, unsigned short* __restrict__ w2p) {
    int i = blockIdx.x * 256 + threadIdx.x;
    if (i < ZERO_N) zero_base[i] = 0.f;
    if (i < DIN * HID / 8) {
        int s0 = i * 8;
        int k = s0 >> 8, n0 = s0 & 255;
        float4 v0 = *(const float4*)(pw1 + s0);
        float4 v1 = *(const float4*)(pw1 + s0 + 4);
        float vv[8] = {v0.x, v0.y, v0.z, v0.w, v1.x, v1.y, v1.z, v1.w};
        int j = k & 7, quad = (k >> 3) & 3, kk = k >> 5;
#pragma unroll
        for (int e = 0; e < 8; ++e) {
            int n = n0 + e, strip = n >> 4, l15 = n & 15;
            w1p[strip * 1024 + kk * 512 + (quad * 16 + l15) * 8 + j] = f2bf(vv[e]);
        }
    }
    if (i < HID * HID / 8) {
        int s0 = i * 8;
        int k = s0 >> 8, n0 = s0 & 255;
        float4 v0 = *(const float4*)(pw2 + s0);
        float4 v1 = *(const float4*)(pw2 + s0 + 4);
        float vv[8] = {v0.x, v0.y, v0.z, v0.w, v1.x, v1.y, v1.z, v1.w};
        int j = k & 7, quad = (k >> 3) & 3, kk = k >> 5;
#pragma unroll
        for (int e = 0; e < 8; ++e) {
            int n = n0 + e, strip = n >> 4, l15 = n & 15;
            w2p[strip * 4096 + kk * 512 + (quad * 16 + l15) * 8 + j] = f2bf(vv[e]);
        }
    }
}

// ---- kernel 1: phi (2 bf16 MFMA layers) + masked pool ----
// 256 thr = 4 waves; wave tile = 64 rows x 64 cols (4 f-blocks x 4 j-blocks).
__launch_bounds__(256, 3)
__global__ void phi_pool(const float* __restrict__ x, const int* __restrict__ mask,
                         const float* __restrict__ pb1, const float* __restrict__ pb2,
                         const unsigned short* __restrict__ w1p,
                         const unsigned short* __restrict__ w2p,
                         float* __restrict__ pooled, int* __restrict__ cnts) {
    __shared__ unsigned short xs[MT * XPAD];    // 9.2 KB
    __shared__ unsigned short h1s[MT * HPAD];   // 33.8 KB
    __shared__ short vlist[VMAX];
    __shared__ int cnt_s;

    const int b = blockIdx.x, sp = blockIdx.y;
    const int t = threadIdx.x;
    const int lane = t & 63, wq = t >> 6;       // wave owns cols wq*64..+63
    const int quad = lane >> 4, l15 = lane & 15;

    const int start = (sp * NN) / SPLIT, end = ((sp + 1) * NN) / SPLIT;

    if (t == 0) cnt_s = 0;
    __syncthreads();
    for (int n = start + t; n < end; n += 256)
        if (mask[b * NN + n] != 0) { int idx = atomicAdd(&cnt_s, 1); vlist[idx] = (short)n; }
    __syncthreads();
    const int cnt = cnt_s;
    if (t == 0) atomicAdd(&cnts[b], cnt);

    float bias1[4], bias2[4];
#pragma unroll
    for (int j = 0; j < 4; ++j) {
        int c = wq * 64 + j * 16 + l15;
        bias1[j] = pb1[c]; bias2[j] = pb2[c];
    }
    float pool[4] = {0.f, 0.f, 0.f, 0.f};

    const float* xb = x + (size_t)b * NN * DIN;
    const uint4* w1q = (const uint4*)w1p;
    const uint4* w2q = (const uint4*)w2p;

    for (int base = 0; base < cnt; base += MT) {
        const int rows = min(MT, cnt - base);
        __syncthreads();                        // prior tile's readers done

        // ---- gather x rows -> bf16 LDS tile (zeros for pad rows) ----
        {
            int r = t >> 2, c0 = (t & 3) * 16;
            float fv[16];
#pragma unroll
            for (int i = 0; i < 16; ++i) fv[i] = 0.f;
            if (r < rows) {
                const float4* s4 = (const float4*)(xb + (size_t)vlist[base + r] * DIN + c0);
                float4 a = s4[0], bq = s4[1], cq = s4[2], dq = s4[3];
                fv[0]=a.x; fv[1]=a.y; fv[2]=a.z; fv[3]=a.w;
                fv[4]=bq.x; fv[5]=bq.y; fv[6]=bq.z; fv[7]=bq.w;
                fv[8]=cq.x; fv[9]=cq.y; fv[10]=cq.z; fv[11]=cq.w;
                fv[12]=dq.x; fv[13]=dq.y; fv[14]=dq.z; fv[15]=dq.w;
            }
            unsigned short tmp[16];
#pragma unroll
            for (int i = 0; i < 16; ++i) tmp[i] = f2bf(fv[i]);
            uint4* dst = (uint4*)&xs[r * XPAD + c0];
            dst[0] = ((const uint4*)tmp)[0];
            dst[1] = ((const uint4*)tmp)[1];
        }
        __syncthreads();

        // ---- layer 1: 64 rows x 64 cols per wave, K=64 ----
        f32x4 acc[4][4];
#pragma unroll
        for (int f = 0; f < 4; ++f)
#pragma unroll
            for (int j = 0; j < 4; ++j) acc[f][j] = (f32x4){0.f, 0.f, 0.f, 0.f};
#pragma unroll
        for (int kk = 0; kk < 2; ++kk) {
            bf16x8 a[4];
#pragma unroll
            for (int f = 0; f < 4; ++f)
                a[f] = *(const bf16x8*)&xs[(f * 16 + l15) * XPAD + kk * 32 + quad * 8];
#pragma unroll
            for (int j = 0; j < 4; ++j) {
                bf16x8 bw = __builtin_bit_cast(bf16x8, w1q[((wq * 4 + j) * 2 + kk) * 64 + lane]);
#pragma unroll
                for (int f = 0; f < 4; ++f)
                    acc[f][j] = __builtin_amdgcn_mfma_f32_16x16x32_bf16(a[f], bw, acc[f][j], 0, 0, 0);
            }
        }
#pragma unroll
        for (int f = 0; f < 4; ++f)
#pragma unroll
            for (int j = 0; j < 4; ++j)
#pragma unroll
                for (int r = 0; r < 4; ++r) {
                    float h = fmaxf(acc[f][j][r] + bias1[j], 0.f);
                    int row = f * 16 + quad * 4 + r;
                    int col = wq * 64 + j * 16 + l15;
                    h1s[row * HPAD + col] = f2bf(h);
                }
        __syncthreads();

        // ---- layer 2: K=256, 1-deep B prefetch ----
        f32x4 acc2[4][4];
#pragma unroll
        for (int f = 0; f < 4; ++f)
#pragma unroll
            for (int j = 0; j < 4; ++j) acc2[f][j] = (f32x4){0.f, 0.f, 0.f, 0.f};

        uint4 bcur[4], bnxt[4];
#pragma unroll
        for (int j = 0; j < 4; ++j)
            bcur[j] = w2q[((wq * 4 + j) * 8 + 0) * 64 + lane];

#pragma unroll
        for (int kk = 0; kk < 8; ++kk) {
            if (kk < 7) {
#pragma unroll
                for (int j = 0; j < 4; ++j)
                    bnxt[j] = w2q[((wq * 4 + j) * 8 + kk + 1) * 64 + lane];
            }
            bf16x8 a[4];
#pragma unroll
            for (int f = 0; f < 4; ++f)
                a[f] = *(const bf16x8*)&h1s[(f * 16 + l15) * HPAD + kk * 32 + quad * 8];
#pragma unroll
            for (int j = 0; j < 4; ++j) {
                bf16x8 bw = __builtin_bit_cast(bf16x8, bcur[j]);
#pragma unroll
                for (int f = 0; f < 4; ++f)
                    acc2[f][j] = __builtin_amdgcn_mfma_f32_16x16x32_bf16(a[f], bw, acc2[f][j], 0, 0, 0);
            }
#pragma unroll
            for (int j = 0; j < 4; ++j) bcur[j] = bnxt[j];
        }

        // predicated relu+pool
#pragma unroll
        for (int f = 0; f < 4; ++f)
#pragma unroll
            for (int r = 0; r < 4; ++r) {
                bool v = (base + f * 16 + quad * 4 + r) < cnt;
#pragma unroll
                for (int j = 0; j < 4; ++j) {
                    float h = fmaxf(acc2[f][j][r] + bias2[j], 0.f);
                    pool[j] += v ? h : 0.f;
                }
            }
    }

#pragma unroll
    for (int j = 0; j < 4; ++j) {
        float v = pool[j];
        v += __shfl_xor(v, 16, 64);
        v += __shfl_xor(v, 32, 64);
        if (quad == 0) atomicAdd(&pooled[b * HID + wq * 64 + j * 16 + l15], v);
    }
}

// ---- kernel 2: folded pw3 + rho chain, fp32, coalesced float4 weights ----
// 512 thr: c = t&63 (4 cols), s = t>>6 (k-octant of 32). Partials via LDS.
__device__ inline float4 dotseg(const float* __restrict__ buf, const float* __restrict__ W,
                                int c, int s) {
    const float4* W4 = (const float4*)W;       // rows of 64 float4 (N=256)
    float4 acc = make_float4(0.f, 0.f, 0.f, 0.f);
#pragma unroll 8
    for (int i = 0; i < 32; ++i) {
        int k = s * 32 + i;
        float bk = buf[k];
        float4 w = W4[(size_t)k * 64 + c];
        acc.x = fmaf(bk, w.x, acc.x);
        acc.y = fmaf(bk, w.y, acc.y);
        acc.z = fmaf(bk, w.z, acc.z);
        acc.w = fmaf(bk, w.w, acc.w);
    }
    return acc;
}

__launch_bounds__(512, 2)
__global__ void rho(const float* __restrict__ pooled, const int* __restrict__ cnts,
                    const float* __restrict__ pw3, const float* __restrict__ pb3,
                    const float* __restrict__ rw1, const float* __restrict__ rb1,
                    const float* __restrict__ rw2, const float* __restrict__ rb2,
                    const float* __restrict__ rw3, const float* __restrict__ rb3,
                    float* __restrict__ out) {
    __shared__ float bufA[HID], bufB[HID];
    __shared__ float part[8][HID];             // 8 KB
    const int b = blockIdx.x, t = threadIdx.x;
    const int c = t & 63, s = t >> 6;
    const int cnt = cnts[b];
    if (t < HID) bufA[t] = pooled[b * HID + t];
    __syncthreads();

    // folded phi-3: bufB = bufA @ pw3 + cnt*pb3
    {
        float4 p = dotseg(bufA, pw3, c, s);
        ((float4*)part[s])[c] = p;
        __syncthreads();
        if (t < HID) {
            float v = (float)cnt * pb3[t];
#pragma unroll
            for (int g = 0; g < 8; ++g) v += part[g][t];
            bufB[t] = v;
        }
        __syncthreads();
    }
    // rho-1
    {
        float4 p = dotseg(bufB, rw1, c, s);
        ((float4*)part[s])[c] = p;
        __syncthreads();
        if (t < HID) {
            float v = rb1[t];
#pragma unroll
            for (int g = 0; g < 8; ++g) v += part[g][t];
            bufA[t] = fmaxf(v, 0.f);
        }
        __syncthreads();
    }
    // rho-2
    {
        float4 p = dotseg(bufA, rw2, c, s);
        ((float4*)part[s])[c] = p;
        __syncthreads();
        if (t < HID) {
            float v = rb2[t];
#pragma unroll
            for (int g = 0; g < 8; ++g) v += part[g][t];
            bufB[t] = fmaxf(v, 0.f);
        }
        __syncthreads();
    }
    // rho-3 (N=128): c4 = t&31 (4 cols), s4 = t>>5 (16 k-segs of 16)
    {
        const int c4 = t & 31, s4 = t >> 5;
        const float4* W4 = (const float4*)rw3;  // rows of 32 float4
        float4 acc = make_float4(0.f, 0.f, 0.f, 0.f);
#pragma unroll 8
        for (int i = 0; i < 16; ++i) {
            int k = s4 * 16 + i;
            float bk = bufB[k];
            float4 w = W4[(size_t)k * 32 + c4];
            acc.x = fmaf(bk, w.x, acc.x);
            acc.y = fmaf(bk, w.y, acc.y);
            acc.z = fmaf(bk, w.z, acc.z);
            acc.w = fmaf(bk, w.w, acc.w);
        }
        float* part2 = &part[0][0];             // reuse as [16][128]
        ((float4*)(part2 + s4 * DOUT))[c4] = acc;
        __syncthreads();
        if (t < DOUT) {
            float v = rb3[t];
#pragma unroll
            for (int g = 0; g < 16; ++g) v += part2[g * DOUT + t];
            out[b * DOUT + t] = (cnt > 0) ? v : 0.f;
        }
    }
}
} // namespace

extern "C" void kernel_launch(void* const* d_in, const int* in_sizes, int n_in,
                              void* d_out, int out_size, void* d_ws, size_t ws_size,
                              hipStream_t stream) {
    const float* x    = (const float*)d_in[0];
    const int*   mask = (const int*)  d_in[1];
    const float* pw1  = (const float*)d_in[2];
    const float* pb1  = (const float*)d_in[3];
    const float* pw2  = (const float*)d_in[4];
    const float* pb2  = (const float*)d_in[5];
    const float* pw3  = (const float*)d_in[6];
    const float* pb3  = (const float*)d_in[7];
    const float* rw1  = (const float*)d_in[8];
    const float* rb1  = (const float*)d_in[9];
    const float* rw2  = (const float*)d_in[10];
    const float* rb2  = (const float*)d_in[11];
    const float* rw3  = (const float*)d_in[12];
    const float* rb3  = (const float*)d_in[13];
    float* out = (float*)d_out;

    float* pooled       = (float*)((char*)d_ws + POOLED_OFF);
    int*   cnts         = (int*)  ((char*)d_ws + CNTS_OFF);
    unsigned short* w1p = (unsigned short*)((char*)d_ws + PW1_OFF);
    unsigned short* w2p = (unsigned short*)((char*)d_ws + PW2_OFF);

    prep<<<dim3((ZERO_N + 255) / 256), dim3(256), 0, stream>>>(pw1, pw2, (float*)d_ws, w1p, w2p);
    phi_pool<<<dim3(NB, SPLIT), dim3(256), 0, stream>>>(x, mask, pb1, pb2, w1p, w2p, pooled, cnts);
    rho<<<dim3(NB), dim3(512), 0, stream>>>(pooled, cnts, pw3, pb3,
                                            rw1, rb1, rw2, rb2, rw3, rb3, out);
}

// Round 5
// 145.339 us; speedup vs baseline: 2.0721x; 1.3970x over previous
//
#include <hip/hip_runtime.h>

namespace {
constexpr int NB = 256, NN = 1024, DIN = 64, HID = 256, DOUT = 128;
constexpr int MT = 64;               // rows per tile

typedef __attribute__((ext_vector_type(8))) short bf16x8;
typedef __attribute__((ext_vector_type(4))) float f32x4;

// ws: w1p [DIN*HID] bf16 (32 KB), w2p [HID*HID] bf16 (128 KB)
constexpr size_t PW1_OFF = 0;
constexpr size_t PW2_OFF = (size_t)DIN * HID * 2;

__device__ inline unsigned short f2bf(float f) {   // RNE float->bf16
    union { float f; unsigned u; } v; v.f = f;
    unsigned r = v.u + 0x7FFF + ((v.u >> 16) & 1);
    return (unsigned short)(r >> 16);
}

// ---- kernel 0: pack W1/W2 into MFMA B-frag order (coalesced reads, scattered 2B stores) ----
// B-frag (16x16x32): lane holds W[k0+(lane>>4)*8+j][n0+(lane&15)], j=0..7.
// w1p shorts: strip*1024 + kk*512 + lane*8 + j   (strip=n>>4, kk=k>>5)
// w2p shorts: strip*4096 + kk*512 + lane*8 + j
__global__ void prep(const float* __restrict__ pw1, const float* __restrict__ pw2,
                     unsigned short* __restrict__ w1p, unsigned short* __restrict__ w2p) {
    int i = blockIdx.x * 256 + threadIdx.x;        // 32 blocks x 256 = 8192
    if (i < DIN * HID / 8) {
        int s0 = i * 8;
        int k = s0 >> 8, n0 = s0 & 255;
        float4 v0 = *(const float4*)(pw1 + s0);
        float4 v1 = *(const float4*)(pw1 + s0 + 4);
        float vv[8] = {v0.x, v0.y, v0.z, v0.w, v1.x, v1.y, v1.z, v1.w};
        int j = k & 7, quad = (k >> 3) & 3, kk = k >> 5;
#pragma unroll
        for (int e = 0; e < 8; ++e) {
            int n = n0 + e, strip = n >> 4, l15 = n & 15;
            w1p[strip * 1024 + kk * 512 + (quad * 16 + l15) * 8 + j] = f2bf(vv[e]);
        }
    }
    if (i < HID * HID / 8) {
        int s0 = i * 8;
        int k = s0 >> 8, n0 = s0 & 255;
        float4 v0 = *(const float4*)(pw2 + s0);
        float4 v1 = *(const float4*)(pw2 + s0 + 4);
        float vv[8] = {v0.x, v0.y, v0.z, v0.w, v1.x, v1.y, v1.z, v1.w};
        int j = k & 7, quad = (k >> 3) & 3, kk = k >> 5;
#pragma unroll
        for (int e = 0; e < 8; ++e) {
            int n = n0 + e, strip = n >> 4, l15 = n & 15;
            w2p[strip * 4096 + kk * 512 + (quad * 16 + l15) * 8 + j] = f2bf(vv[e]);
        }
    }
}

// fp32 GEMV segment for the rho chain: 512 thr, c=t&63 (4 cols), s=t>>6 (k-octant)
__device__ inline float4 dotseg(const float* __restrict__ buf, const float* __restrict__ W,
                                int c, int s) {
    const float4* W4 = (const float4*)W;           // rows of 64 float4 (N=256)
    float4 acc = make_float4(0.f, 0.f, 0.f, 0.f);
#pragma unroll 8
    for (int i = 0; i < 32; ++i) {
        int k = s * 32 + i;
        float bk = buf[k];
        float4 w = W4[(size_t)k * 64 + c];
        acc.x = fmaf(bk, w.x, acc.x);
        acc.y = fmaf(bk, w.y, acc.y);
        acc.z = fmaf(bk, w.z, acc.z);
        acc.w = fmaf(bk, w.w, acc.w);
    }
    return acc;
}

// ---- fused kernel: compaction -> phi (MFMA, W-in-regs) -> pool -> rho ----
// 1 block per batch, 512 threads (8 waves). Wave w owns output cols w*32..w*32+31.
__launch_bounds__(512, 2)
__global__ void deepset(const float* __restrict__ x, const int* __restrict__ mask,
                        const float* __restrict__ pb1, const float* __restrict__ pb2,
                        const unsigned short* __restrict__ w1p,
                        const unsigned short* __restrict__ w2p,
                        const float* __restrict__ pw3, const float* __restrict__ pb3,
                        const float* __restrict__ rw1, const float* __restrict__ rb1,
                        const float* __restrict__ rw2, const float* __restrict__ rb2,
                        const float* __restrict__ rw3, const float* __restrict__ rb3,
                        float* __restrict__ out)
{
    __shared__ unsigned short xs[2][MT * 64];   // 16 KB, XOR-swizzled, double-buffered
    __shared__ unsigned short h1s[MT * 256];    // 32 KB, XOR-swizzled
    __shared__ short vlist[NN];                 // 2 KB
    __shared__ float pooledS[HID];              // 1 KB
    __shared__ float part[8][HID];              // 8 KB
    __shared__ float bufB[HID], bufC[HID];      // 2 KB
    __shared__ int cnt_s;

    const int b = blockIdx.x, t = threadIdx.x;
    const int lane = t & 63, wq = t >> 6;
    const int quad = lane >> 4, l15 = lane & 15;

    // ---- compact valid indices (order irrelevant: sum-pool) ----
    if (t == 0) cnt_s = 0;
    __syncthreads();
    if (mask[b * NN + t] != 0)       { int i = atomicAdd(&cnt_s, 1); vlist[i] = (short)t; }
    if (mask[b * NN + t + 512] != 0) { int i = atomicAdd(&cnt_s, 1); vlist[i] = (short)(t + 512); }
    __syncthreads();
    const int cnt = cnt_s;

    // ---- W fragments -> registers (once per block; inner loop is LDS+MFMA only) ----
    const uint4* w1q = (const uint4*)w1p;
    const uint4* w2q = (const uint4*)w2p;
    uint4 w1f[2][2], w2f[8][2];
#pragma unroll
    for (int j = 0; j < 2; ++j) {
        int strip = wq * 2 + j;
#pragma unroll
        for (int kk = 0; kk < 2; ++kk) w1f[kk][j] = w1q[(strip * 2 + kk) * 64 + lane];
#pragma unroll
        for (int kk = 0; kk < 8; ++kk) w2f[kk][j] = w2q[(strip * 8 + kk) * 64 + lane];
    }
    float bias1[2], bias2[2];
#pragma unroll
    for (int j = 0; j < 2; ++j) {
        int c = wq * 32 + j * 16 + l15;
        bias1[j] = pb1[c]; bias2[j] = pb2[c];
    }

    float pool[2] = {0.f, 0.f};
    const float* xb = x + (size_t)b * NN * DIN;
    const int gr = t >> 3, seg8 = t & 7;                 // gather: row, 16B-block
    const int xoff = gr * 64 + ((seg8 ^ (gr & 7)) << 3); // swizzled xs offset (shorts)

    // ---- preload tile 0 ----
    {
        float4 a0 = make_float4(0.f,0.f,0.f,0.f), a1 = a0;
        if (gr < min(MT, cnt)) {
            const float4* p = (const float4*)(xb + (size_t)vlist[gr] * DIN + seg8 * 8);
            a0 = p[0]; a1 = p[1];
        }
        unsigned short tmp[8] = {f2bf(a0.x),f2bf(a0.y),f2bf(a0.z),f2bf(a0.w),
                                 f2bf(a1.x),f2bf(a1.y),f2bf(a1.z),f2bf(a1.w)};
        *(uint4*)&xs[0][xoff] = *(const uint4*)tmp;
    }

    int cur = 0;
    for (int base = 0; base < cnt; base += MT) {
        __syncthreads();                                  // B_top: xs[cur] visible, h1s readers done

        // ---- layer 1: xs -> h1s (K=64) ----
        f32x4 acc[4][2];
#pragma unroll
        for (int f = 0; f < 4; ++f)
#pragma unroll
            for (int j = 0; j < 2; ++j) acc[f][j] = (f32x4){0.f,0.f,0.f,0.f};
#pragma unroll
        for (int kk = 0; kk < 2; ++kk) {
            bf16x8 a[4];
#pragma unroll
            for (int f = 0; f < 4; ++f)
                a[f] = *(const bf16x8*)&xs[cur][(f*16 + l15)*64 + (((kk*4 + quad) ^ (l15 & 7)) << 3)];
#pragma unroll
            for (int j = 0; j < 2; ++j) {
                bf16x8 bw = __builtin_bit_cast(bf16x8, w1f[kk][j]);
#pragma unroll
                for (int f = 0; f < 4; ++f)
                    acc[f][j] = __builtin_amdgcn_mfma_f32_16x16x32_bf16(a[f], bw, acc[f][j], 0, 0, 0);
            }
        }
#pragma unroll
        for (int f = 0; f < 4; ++f)
#pragma unroll
            for (int j = 0; j < 2; ++j) {
                int col = wq * 32 + j * 16 + l15, kb = col >> 3, cl = col & 7;
#pragma unroll
                for (int r = 0; r < 4; ++r) {
                    int row = f * 16 + quad * 4 + r;
                    float h = fmaxf(acc[f][j][r] + bias1[j], 0.f);
                    h1s[row * 256 + ((kb ^ (row & 7)) << 3) + cl] = f2bf(h);
                }
            }

        // ---- prefetch next x tile into regs (drains at B_mid, covered by L1) ----
        float4 n0 = make_float4(0.f,0.f,0.f,0.f), n1 = n0;
        const bool hn = (base + MT) < cnt;
        if (hn && gr < cnt - (base + MT)) {
            const float4* p = (const float4*)(xb + (size_t)vlist[base + MT + gr] * DIN + seg8 * 8);
            n0 = p[0]; n1 = p[1];
        }
        __syncthreads();                                  // B_mid: h1s visible

        // ---- layer 2: h1s -> pool (K=256), W2 from registers ----
        f32x4 acc2[4][2];
#pragma unroll
        for (int f = 0; f < 4; ++f)
#pragma unroll
            for (int j = 0; j < 2; ++j) acc2[f][j] = (f32x4){0.f,0.f,0.f,0.f};
#pragma unroll
        for (int kk = 0; kk < 8; ++kk) {
            bf16x8 a[4];
#pragma unroll
            for (int f = 0; f < 4; ++f)
                a[f] = *(const bf16x8*)&h1s[(f*16 + l15)*256 + (((kk*4 + quad) ^ (l15 & 7)) << 3)];
#pragma unroll
            for (int j = 0; j < 2; ++j) {
                bf16x8 bw = __builtin_bit_cast(bf16x8, w2f[kk][j]);
#pragma unroll
                for (int f = 0; f < 4; ++f)
                    acc2[f][j] = __builtin_amdgcn_mfma_f32_16x16x32_bf16(a[f], bw, acc2[f][j], 0, 0, 0);
            }
        }
#pragma unroll
        for (int f = 0; f < 4; ++f)
#pragma unroll
            for (int r = 0; r < 4; ++r) {
                bool v = (base + f * 16 + quad * 4 + r) < cnt;
#pragma unroll
                for (int j = 0; j < 2; ++j) {
                    float h = fmaxf(acc2[f][j][r] + bias2[j], 0.f);
                    pool[j] += v ? h : 0.f;
                }
            }

        if (hn) {
            unsigned short tmp[8] = {f2bf(n0.x),f2bf(n0.y),f2bf(n0.z),f2bf(n0.w),
                                     f2bf(n1.x),f2bf(n1.y),f2bf(n1.z),f2bf(n1.w)};
            *(uint4*)&xs[cur ^ 1][xoff] = *(const uint4*)tmp;
        }
        cur ^= 1;
    }

    // ---- pool reduce: cross-quad shuffle, cols are wave-disjoint ----
#pragma unroll
    for (int j = 0; j < 2; ++j) {
        float v = pool[j];
        v += __shfl_xor(v, 16, 64);
        v += __shfl_xor(v, 32, 64);
        if (quad == 0) pooledS[wq * 32 + j * 16 + l15] = v;
    }
    __syncthreads();

    // ---- fused rho (fp32): folded pw3 + 3-layer chain ----
    const int c = t & 63, s = t >> 6;
    {
        float4 p = dotseg(pooledS, pw3, c, s);
        ((float4*)part[s])[c] = p;
        __syncthreads();
        if (t < HID) {
            float v = (float)cnt * pb3[t];
#pragma unroll
            for (int g = 0; g < 8; ++g) v += part[g][t];
            bufB[t] = v;
        }
        __syncthreads();
    }
    {
        float4 p = dotseg(bufB, rw1, c, s);
        ((float4*)part[s])[c] = p;
        __syncthreads();
        if (t < HID) {
            float v = rb1[t];
#pragma unroll
            for (int g = 0; g < 8; ++g) v += part[g][t];
            bufC[t] = fmaxf(v, 0.f);
        }
        __syncthreads();
    }
    {
        float4 p = dotseg(bufC, rw2, c, s);
        ((float4*)part[s])[c] = p;
        __syncthreads();
        if (t < HID) {
            float v = rb2[t];
#pragma unroll
            for (int g = 0; g < 8; ++g) v += part[g][t];
            bufB[t] = fmaxf(v, 0.f);
        }
        __syncthreads();
    }
    {   // final layer, N=128: c4=t&31 (4 cols), s4=t>>5 (16 k-segs)
        const int c4 = t & 31, s4 = t >> 5;
        const float4* W4 = (const float4*)rw3;
        float4 acc = make_float4(0.f, 0.f, 0.f, 0.f);
#pragma unroll 8
        for (int i = 0; i < 16; ++i) {
            int k = s4 * 16 + i;
            float bk = bufB[k];
            float4 w = W4[(size_t)k * 32 + c4];
            acc.x = fmaf(bk, w.x, acc.x);
            acc.y = fmaf(bk, w.y, acc.y);
            acc.z = fmaf(bk, w.z, acc.z);
            acc.w = fmaf(bk, w.w, acc.w);
        }
        float* part2 = &part[0][0];                       // reuse as [16][128]
        ((float4*)(part2 + s4 * DOUT))[c4] = acc;
        __syncthreads();
        if (t < DOUT) {
            float v = rb3[t];
#pragma unroll
            for (int g = 0; g < 16; ++g) v += part2[g * DOUT + t];
            out[b * DOUT + t] = (cnt > 0) ? v : 0.f;
        }
    }
}
} // namespace

extern "C" void kernel_launch(void* const* d_in, const int* in_sizes, int n_in,
                              void* d_out, int out_size, void* d_ws, size_t ws_size,
                              hipStream_t stream) {
    const float* x    = (const float*)d_in[0];
    const int*   mask = (const int*)  d_in[1];
    const float* pw1  = (const float*)d_in[2];
    const float* pb1  = (const float*)d_in[3];
    const float* pw2  = (const float*)d_in[4];
    const float* pb2  = (const float*)d_in[5];
    const float* pw3  = (const float*)d_in[6];
    const float* pb3  = (const float*)d_in[7];
    const float* rw1  = (const float*)d_in[8];
    const float* rb1  = (const float*)d_in[9];
    const float* rw2  = (const float*)d_in[10];
    const float* rb2  = (const float*)d_in[11];
    const float* rw3  = (const float*)d_in[12];
    const float* rb3  = (const float*)d_in[13];
    float* out = (float*)d_out;

    unsigned short* w1p = (unsigned short*)((char*)d_ws + PW1_OFF);
    unsigned short* w2p = (unsigned short*)((char*)d_ws + PW2_OFF);

    prep<<<dim3(32), dim3(256), 0, stream>>>(pw1, pw2, w1p, w2p);
    deepset<<<dim3(NB), dim3(512), 0, stream>>>(x, mask, pb1, pb2, w1p, w2p,
                                                pw3, pb3, rw1, rb1, rw2, rb2, rw3, rb3, out);
}